// Round 8
// baseline (286.298 us; speedup 1.0000x reference)
//
#include <hip/hip_runtime.h>
#include <hip/hip_bf16.h>
#include <cstdint>

#define NB 2
#define NSEQ 2048
#define NSEQP 2176   // padded vt row stride
#define NDIM 512
#define NHEAD 8
#define DHEAD 32
#define NINNER 256
#define NQKV 768
#define LNEPS 1e-5f
#define QSCALE 0.17677669529663687f

typedef short short8 __attribute__((ext_vector_type(8)));
typedef float f32x4 __attribute__((ext_vector_type(4)));
typedef unsigned int u32x4 __attribute__((ext_vector_type(4)));
typedef unsigned int u32x2 __attribute__((ext_vector_type(2)));
typedef unsigned short u16;
typedef unsigned int u32;

__device__ __forceinline__ f32x4 mfma16(short8 a, short8 b, f32x4 c) {
    return __builtin_amdgcn_mfma_f32_16x16x32_bf16(a, b, c, 0, 0, 0);
}

__device__ __forceinline__ u16 f2bf(float a) {
    union { float f; u32 u; } x; x.f = a;
    u32 r = x.u + 0x7fffu + ((x.u >> 16) & 1u);
    return (u16)(r >> 16);
}
__device__ __forceinline__ float bf2f(u16 h) {
    union { float f; u32 u; } x; x.u = ((u32)h) << 16; return x.f;
}
__device__ __forceinline__ void split2(float a, u16& hi, u16& lo) {
    hi = f2bf(a);
    lo = f2bf(a - bf2f(hi));
}
__device__ __forceinline__ u32 pk2(float a, float b) {
    return (u32)f2bf(a) | ((u32)f2bf(b) << 16);
}

// ---------------- Kernel 1: LayerNorm + bf16 hi/lo split ----------------
__global__ __launch_bounds__(256) void ln_kernel(
    const float* __restrict__ x, const float* __restrict__ gamma,
    u32* __restrict__ xn_hi, u32* __restrict__ xn_lo)
{
    const int row = blockIdx.x;
    const int t = threadIdx.x;
    const float2 v = ((const float2*)(x + (size_t)row * NDIM))[t];
    float s1 = v.x + v.y;
    float s2 = v.x * v.x + v.y * v.y;
    #pragma unroll
    for (int off = 32; off >= 1; off >>= 1) {
        s1 += __shfl_down(s1, off);
        s2 += __shfl_down(s2, off);
    }
    __shared__ float a1[4], a2[4];
    if ((t & 63) == 0) { a1[t >> 6] = s1; a2[t >> 6] = s2; }
    __syncthreads();
    const float ts1 = a1[0] + a1[1] + a1[2] + a1[3];
    const float ts2 = a2[0] + a2[1] + a2[2] + a2[3];
    const float mu = ts1 * (1.0f / NDIM);
    const float var = ts2 * (1.0f / NDIM) - mu * mu;
    const float rs = rsqrtf(var + LNEPS);
    const float2 g = ((const float2*)gamma)[t];
    u16 h0, l0, h1, l1;
    split2((v.x - mu) * rs * g.x, h0, l0);
    split2((v.y - mu) * rs * g.y, h1, l1);
    xn_hi[(size_t)row * (NDIM / 2) + t] = (u32)h0 | ((u32)h1 << 16);
    xn_lo[(size_t)row * (NDIM / 2) + t] = (u32)l0 | ((u32)l1 << 16);
}

// ---------------- Weight transpose + split, both weights in one launch ----------------
__global__ __launch_bounds__(256) void wtrans_kernel(
    const float* __restrict__ wq, u16* __restrict__ wqT_hi, u16* __restrict__ wqT_lo,
    const float* __restrict__ wo, u16* __restrict__ woT_hi, u16* __restrict__ woT_lo)
{
    __shared__ __align__(16) u16 th[64][72], tl[64][72];
    const int t = threadIdx.x;
    const float* w; u16 *wT_hi, *wT_lo; int K, N, k0, n0;
    if (blockIdx.x < 96) {
        w = wq; wT_hi = wqT_hi; wT_lo = wqT_lo; K = NDIM; N = NQKV;
        k0 = (blockIdx.x & 7) * 64; n0 = (blockIdx.x >> 3) * 64;
    } else {
        const int b = blockIdx.x - 96;
        w = wo; wT_hi = woT_hi; wT_lo = woT_lo; K = NINNER; N = NDIM;
        k0 = (b & 3) * 64; n0 = (b >> 2) * 64;
    }
    {
        const int k = t >> 2, c = (t & 3) * 16;
        const float* src = w + (size_t)(k0 + k) * N + n0 + c;
        #pragma unroll
        for (int jj = 0; jj < 4; jj++) {
            const f32x4 w4 = *(const f32x4*)(src + jj * 4);
            #pragma unroll
            for (int e = 0; e < 4; e++) {
                u16 hh, ll;
                split2(w4[e], hh, ll);
                th[k][c + jj * 4 + e] = hh;
                tl[k][c + jj * 4 + e] = ll;
            }
        }
    }
    __syncthreads();
    {
        const int n = t >> 2, kc = (t & 3) * 16;
        u16 hb[16], lb[16];
        #pragma unroll
        for (int j = 0; j < 16; j++) { hb[j] = th[kc + j][n]; lb[j] = tl[kc + j][n]; }
        u16* dh = wT_hi + (size_t)(n0 + n) * K + k0 + kc;
        u16* dl = wT_lo + (size_t)(n0 + n) * K + k0 + kc;
        *(short8*)dh = *(short8*)hb;
        *(short8*)(dh + 8) = *(short8*)(hb + 8);
        *(short8*)dl = *(short8*)lb;
        *(short8*)(dl + 8) = *(short8*)(lb + 8);
    }
}

// ---------------- V transpose: v[bh][N][32] bf16 -> vt[bh][32][NSEQP] (padded) ----------------
__global__ __launch_bounds__(256) void vtrans_kernel(
    const u16* __restrict__ v, u16* __restrict__ vt)
{
    __shared__ __align__(16) u16 sh[64][40];
    const int t = threadIdx.x;
    const int n0 = blockIdx.x * 64;
    const int bh = blockIdx.y;
    {
        const int n = t >> 2, c = (t & 3) * 8;
        *(short8*)&sh[n][c] = *(const short8*)(v + ((size_t)bh * NSEQ + n0 + n) * DHEAD + c);
    }
    __syncthreads();
    {
        const int d = t >> 3, nc = (t & 7) * 8;
        u16 buf[8];
        #pragma unroll
        for (int j = 0; j < 8; j++) buf[j] = sh[nc + j][d];
        *(short8*)(vt + ((size_t)bh * DHEAD + d) * NSEQP + n0 + nc) = *(short8*)buf;
    }
}

// ---------------- Kernel 2: QKV GEMM (64x64 tile, 4 waves, 12 MFMA/wave-iter) ----------------
__global__ __launch_bounds__(256, 4) void qkv_kernel(
    const u16* __restrict__ xn_hi, const u16* __restrict__ xn_lo,
    const u16* __restrict__ wT_hi, const u16* __restrict__ wT_lo,
    u16* __restrict__ q_hi, u16* __restrict__ q_lo,
    u16* __restrict__ k_hi, u16* __restrict__ k_lo,
    u16* __restrict__ v)
{
    __shared__ __align__(16) u16 Ah[64][40], Al[64][40], Bh[64][40], Bl[64][40];
    const int t = threadIdx.x;
    const int wave = t >> 6, lane = t & 63;
    const int lrow = lane & 15, lquad = lane >> 4;
    const int rowBase = blockIdx.x * 64;
    const int colBase = blockIdx.y * 64;
    const int wm = (wave & 1) * 32;
    const int wn = (wave >> 1) * 32;
    const int kf = lquad * 8;
    const f32x4 zero = {0.f, 0.f, 0.f, 0.f};
    f32x4 acc[2][2];
    acc[0][0] = zero; acc[0][1] = zero; acc[1][0] = zero; acc[1][1] = zero;

    const int sr = t >> 2, sc = (t & 3) * 8;

    for (int k0 = 0; k0 < NDIM; k0 += 32) {
        __syncthreads();
        *(short8*)&Ah[sr][sc] = *(const short8*)(xn_hi + (size_t)(rowBase + sr) * NDIM + k0 + sc);
        *(short8*)&Al[sr][sc] = *(const short8*)(xn_lo + (size_t)(rowBase + sr) * NDIM + k0 + sc);
        *(short8*)&Bh[sr][sc] = *(const short8*)(wT_hi + (size_t)(colBase + sr) * NDIM + k0 + sc);
        *(short8*)&Bl[sr][sc] = *(const short8*)(wT_lo + (size_t)(colBase + sr) * NDIM + k0 + sc);
        __syncthreads();
        const short8 a0h = *(const short8*)&Ah[wm + lrow][kf];
        const short8 a0l = *(const short8*)&Al[wm + lrow][kf];
        const short8 a1h = *(const short8*)&Ah[wm + 16 + lrow][kf];
        const short8 a1l = *(const short8*)&Al[wm + 16 + lrow][kf];
        const short8 b0h = *(const short8*)&Bh[wn + lrow][kf];
        const short8 b0l = *(const short8*)&Bl[wn + lrow][kf];
        const short8 b1h = *(const short8*)&Bh[wn + 16 + lrow][kf];
        const short8 b1l = *(const short8*)&Bl[wn + 16 + lrow][kf];
        acc[0][0] = mfma16(a0h, b0h, acc[0][0]); acc[0][0] = mfma16(a0h, b0l, acc[0][0]); acc[0][0] = mfma16(a0l, b0h, acc[0][0]);
        acc[0][1] = mfma16(a0h, b1h, acc[0][1]); acc[0][1] = mfma16(a0h, b1l, acc[0][1]); acc[0][1] = mfma16(a0l, b1h, acc[0][1]);
        acc[1][0] = mfma16(a1h, b0h, acc[1][0]); acc[1][0] = mfma16(a1h, b0l, acc[1][0]); acc[1][0] = mfma16(a1l, b0h, acc[1][0]);
        acc[1][1] = mfma16(a1h, b1h, acc[1][1]); acc[1][1] = mfma16(a1h, b1l, acc[1][1]); acc[1][1] = mfma16(a1l, b1h, acc[1][1]);
    }

    #pragma unroll
    for (int mi = 0; mi < 2; mi++) {
        #pragma unroll
        for (int ni = 0; ni < 2; ni++) {
            #pragma unroll
            for (int r = 0; r < 4; r++) {
                const int grow = rowBase + wm + mi * 16 + lquad * 4 + r;
                const int gcol = colBase + wn + ni * 16 + lrow;
                const float val = acc[mi][ni][r];
                const int bidx = grow >> 11;
                const int n = grow & (NSEQ - 1);
                const int sec = gcol >> 8;          // 0=q 1=k 2=v
                const int idx = gcol & 255;
                const int head = idx >> 5, d = idx & 31;
                const int bh = bidx * NHEAD + head;
                if (sec == 0) {
                    u16 hh, ll;
                    split2(val * QSCALE, hh, ll);
                    const size_t a = ((size_t)bh * NSEQ + n) * DHEAD + d;
                    q_hi[a] = hh; q_lo[a] = ll;
                } else if (sec == 1) {
                    u16 hh, ll;
                    split2(val, hh, ll);
                    const size_t a = ((size_t)bh * NSEQ + n) * DHEAD + d;
                    k_hi[a] = hh; k_lo[a] = ll;
                } else {
                    v[((size_t)bh * NSEQ + n) * DHEAD + d] = f2bf(val);
                }
            }
        }
    }
}

// ---------------- Kernel 3: flash attention, LDS-staged bias ----------------
// Block = 512 threads = 8 waves, one (batch,head), 32-query tile.
// Grid 64x16 = 1024 blocks. All waves walk the SAME 128-key window per
// iteration; wave w = (qpair = w&1 -> q-frag 16 rows, ksub = w>>1 ->
// 32-key subtile). Bias[32 rows x 128 keys] (16KB) is staged into LDS
// per iteration with COALESCED loads: thread t reads 32B contiguous of
// row qb+(t>>4); each block reads 32 fully-sequential row streams.
// T14 split: issue global loads -> regs before compute, write LDS after
// barrier (HBM latency hides under QK/PV). Softmax reads bias from LDS
// (row stride 132 floats -> 2-way bank aliasing = free).
__global__ __launch_bounds__(512) void attn_kernel(
    const u16* __restrict__ q_hi, const u16* __restrict__ q_lo,
    const u16* __restrict__ k_hi, const u16* __restrict__ k_lo,
    const u16* __restrict__ vt,
    const float* __restrict__ bias,
    u16* __restrict__ o_hi, u16* __restrict__ o_lo)
{
    __shared__ __align__(16) float bs_lds[32][132];      // bias tile, padded stride
    __shared__ __align__(16) float cA[2][4][64][4];      // [qpair][ksub][lane][4]
    __shared__ __align__(16) float cB[2][4][64][4];
    __shared__ float cl[2][4][16];
    const int t = threadIdx.x;
    const int wave = t >> 6, lane = t & 63;
    const int lrow = lane & 15, lquad = lane >> 4;
    const int qpair = wave & 1, ksub = wave >> 1;
    const int bh = blockIdx.y;
    const int batch = bh >> 3, head = bh & 7;
    const int qb = blockIdx.x * 32;
    const size_t qkb = (size_t)bh * NSEQ * DHEAD;
    const size_t vtb = (size_t)bh * DHEAD * NSEQP;
    // this wave's single 16-q fragment
    const size_t qoff = (size_t)(qb + qpair * 16 + lrow) * DHEAD + lquad * 8;
    const short8 qh = *(const short8*)(q_hi + qkb + qoff);
    const short8 ql = *(const short8*)(q_lo + qkb + qoff);
    const f32x4 zero = {0.f, 0.f, 0.f, 0.f};
    f32x4 accA = zero, accB = zero;
    float lp = 0.f;
    const int kperm = ((lrow >> 2) << 3) | (lrow & 3);
    // bias staging: thread t covers row qb+(t>>4), 32B at col (t&15)*8
    const int srow = t >> 4, scol = (t & 15) * 8;
    const float* bsrc = bias + (size_t)head * NSEQ * NSEQ + (size_t)(qb + srow) * NSEQ + scol;

    // prologue: stage tile 0
    {
        const f32x4 r0 = *(const f32x4*)(bsrc);
        const f32x4 r1 = *(const f32x4*)(bsrc + 4);
        *(f32x4*)&bs_lds[srow][scol] = r0;
        *(f32x4*)&bs_lds[srow][scol + 4] = r1;
    }
    __syncthreads();

    for (int i = 0; i < 16; i++) {
        const int kt = i * 128 + ksub * 32;
        // K / V loads for this wave's 32-key subtile (L2-resident)
        const size_t kof = (size_t)(kt + kperm) * DHEAD + lquad * 8;
        const short8 k0h = *(const short8*)(k_hi + qkb + kof);
        const short8 k0l = *(const short8*)(k_lo + qkb + kof);
        const short8 k1h = *(const short8*)(k_hi + qkb + kof + 4 * DHEAD);
        const short8 k1l = *(const short8*)(k_lo + qkb + kof + 4 * DHEAD);
        const short8 va0 = *(const short8*)(vt + vtb + (size_t)lrow * NSEQP + kt + lquad * 8);
        const short8 va1 = *(const short8*)(vt + vtb + (size_t)(16 + lrow) * NSEQP + kt + lquad * 8);
        // issue next bias tile loads (HBM) -> registers; in flight through compute
        f32x4 n0 = zero, n1 = zero;
        if (i < 15) {
            n0 = *(const f32x4*)(bsrc + (i + 1) * 128);
            n1 = *(const f32x4*)(bsrc + (i + 1) * 128 + 4);
        }
        // bias for this wave's tile slice from LDS
        const int brow = qpair * 16 + lrow;
        const int bcol = ksub * 32 + lquad * 8;
        const f32x4 b00 = *(const f32x4*)&bs_lds[brow][bcol];
        const f32x4 b01 = *(const f32x4*)&bs_lds[brow][bcol + 4];

        // QK^T (S^T = K.Q^T), softmax numerator, PV
        f32x4 c0 = zero, c1 = zero;
        c0 = mfma16(k0h, qh, c0); c0 = mfma16(k0h, ql, c0); c0 = mfma16(k0l, qh, c0);
        c1 = mfma16(k1h, qh, c1); c1 = mfma16(k1h, ql, c1); c1 = mfma16(k1l, qh, c1);
        f32x4 p0, p1;
        #pragma unroll
        for (int r = 0; r < 4; r++) {
            p0[r] = __expf(c0[r] + b00[r]);
            p1[r] = __expf(c1[r] + b01[r]);
        }
        lp += (p0[0] + p0[1]) + (p0[2] + p0[3]) + (p1[0] + p1[1]) + (p1[2] + p1[3]);
        union { u32x4 u; short8 s; } cv;
        cv.u[0] = pk2(p0[0], p0[1]);
        cv.u[1] = pk2(p0[2], p0[3]);
        cv.u[2] = pk2(p1[0], p1[1]);
        cv.u[3] = pk2(p1[2], p1[3]);
        accA = mfma16(va0, cv.s, accA);
        accB = mfma16(va1, cv.s, accB);

        __syncthreads();                 // all waves done reading bias tile i
        if (i < 15) {
            *(f32x4*)&bs_lds[srow][scol] = n0;
            *(f32x4*)&bs_lds[srow][scol + 4] = n1;
        }
        __syncthreads();                 // tile i+1 ready
    }

    // per-lane lp covers keys quad*8..+7 of this subtile; reduce across quads
    lp += __shfl_xor(lp, 16); lp += __shfl_xor(lp, 32);

    *(f32x4*)&cA[qpair][ksub][lane][0] = accA;
    *(f32x4*)&cB[qpair][ksub][lane][0] = accB;
    if (lquad == 0) {
        cl[qpair][ksub][lrow] = lp;
    }
    __syncthreads();
    if (wave < 4) {
        const int s = wave >> 1, part = wave & 1;   // part 0 -> A (d 0..15), 1 -> B (d 16..31)
        const float (*src)[64][4] = part ? (const float (*)[64][4])cB[s]
                                         : (const float (*)[64][4])cA[s];
        f32x4 sv = *(const f32x4*)&src[0][lane][0];
        #pragma unroll
        for (int w = 1; w < 4; w++) {
            sv += *(const f32x4*)&src[w][lane][0];
        }
        float lt = 0.f;
        #pragma unroll
        for (int w = 0; w < 4; w++) lt += cl[s][w][lrow];
        const float inv = 1.0f / lt;
        const int q = qb + s * 16 + lrow;
        const size_t base = ((size_t)batch * NSEQ + q) * NINNER + head * DHEAD + part * 16 + lquad * 4;
        u16 h[4], l[4];
        #pragma unroll
        for (int r = 0; r < 4; r++) {
            split2(sv[r] * inv, h[r], l[r]);
        }
        *(u32x2*)&o_hi[base] = *(u32x2*)&h[0];
        *(u32x2*)&o_lo[base] = *(u32x2*)&l[0];
    }
}

// ---------------- Kernel 4: output projection (64x64 tile) + bias ----------------
__global__ __launch_bounds__(256, 4) void out_kernel(
    const u16* __restrict__ o_hi, const u16* __restrict__ o_lo,
    const u16* __restrict__ wT_hi, const u16* __restrict__ wT_lo,
    const float* __restrict__ b_out,
    float* __restrict__ out)
{
    __shared__ __align__(16) u16 Ah[64][40], Al[64][40], Bh[64][40], Bl[64][40];
    const int t = threadIdx.x;
    const int wave = t >> 6, lane = t & 63;
    const int lrow = lane & 15, lquad = lane >> 4;
    const int rowBase = blockIdx.x * 64;
    const int colBase = blockIdx.y * 64;
    const int wm = (wave & 1) * 32;
    const int wn = (wave >> 1) * 32;
    const int kf = lquad * 8;
    const f32x4 zero = {0.f, 0.f, 0.f, 0.f};
    f32x4 acc[2][2];
    acc[0][0] = zero; acc[0][1] = zero; acc[1][0] = zero; acc[1][1] = zero;

    const int sr = t >> 2, sc = (t & 3) * 8;

    for (int k0 = 0; k0 < NINNER; k0 += 32) {
        __syncthreads();
        *(short8*)&Ah[sr][sc] = *(const short8*)(o_hi + (size_t)(rowBase + sr) * NINNER + k0 + sc);
        *(short8*)&Al[sr][sc] = *(const short8*)(o_lo + (size_t)(rowBase + sr) * NINNER + k0 + sc);
        *(short8*)&Bh[sr][sc] = *(const short8*)(wT_hi + (size_t)(colBase + sr) * NINNER + k0 + sc);
        *(short8*)&Bl[sr][sc] = *(const short8*)(wT_lo + (size_t)(colBase + sr) * NINNER + k0 + sc);
        __syncthreads();
        const short8 a0h = *(const short8*)&Ah[wm + lrow][kf];
        const short8 a0l = *(const short8*)&Al[wm + lrow][kf];
        const short8 a1h = *(const short8*)&Ah[wm + 16 + lrow][kf];
        const short8 a1l = *(const short8*)&Al[wm + 16 + lrow][kf];
        const short8 b0h = *(const short8*)&Bh[wn + lrow][kf];
        const short8 b0l = *(const short8*)&Bl[wn + lrow][kf];
        const short8 b1h = *(const short8*)&Bh[wn + 16 + lrow][kf];
        const short8 b1l = *(const short8*)&Bl[wn + 16 + lrow][kf];
        acc[0][0] = mfma16(a0h, b0h, acc[0][0]); acc[0][0] = mfma16(a0h, b0l, acc[0][0]); acc[0][0] = mfma16(a0l, b0h, acc[0][0]);
        acc[0][1] = mfma16(a0h, b1h, acc[0][1]); acc[0][1] = mfma16(a0h, b1l, acc[0][1]); acc[0][1] = mfma16(a0l, b1h, acc[0][1]);
        acc[1][0] = mfma16(a1h, b0h, acc[1][0]); acc[1][0] = mfma16(a1h, b0l, acc[1][0]); acc[1][0] = mfma16(a1l, b0h, acc[1][0]);
        acc[1][1] = mfma16(a1h, b1h, acc[1][1]); acc[1][1] = mfma16(a1h, b1l, acc[1][1]); acc[1][1] = mfma16(a1l, b1h, acc[1][1]);
    }

    #pragma unroll
    for (int mi = 0; mi < 2; mi++) {
        #pragma unroll
        for (int ni = 0; ni < 2; ni++) {
            #pragma unroll
            for (int r = 0; r < 4; r++) {
                const int grow = rowBase + wm + mi * 16 + lquad * 4 + r;
                const int gcol = colBase + wn + ni * 16 + lrow;
                out[(size_t)grow * NDIM + gcol] = acc[mi][ni][r] + b_out[gcol];
            }
        }
    }
}

extern "C" void kernel_launch(void* const* d_in, const int* in_sizes, int n_in,
                              void* d_out, int out_size, void* d_ws, size_t ws_size,
                              hipStream_t stream)
{
    (void)in_sizes; (void)n_in; (void)out_size; (void)ws_size;
    const float* x     = (const float*)d_in[0];
    const float* bias  = (const float*)d_in[1];
    const float* gamma = (const float*)d_in[2];
    const float* wqkv  = (const float*)d_in[3];
    const float* wout  = (const float*)d_in[4];
    const float* bout  = (const float*)d_in[5];
    float* out = (float*)d_out;

    char* ws = (char*)d_ws;
    size_t off = 0;
    auto carve = [&](size_t bytes) -> void* {
        void* p = (void*)(ws + off);
        off += (bytes + 255) & ~(size_t)255;
        return p;
    };
    const size_t rows = (size_t)NB * NSEQ;                 // 4096
    const size_t hn = (size_t)NB * NHEAD * NSEQ * DHEAD;   // 1,048,576
    const size_t hnp = (size_t)NB * NHEAD * DHEAD * NSEQP; // padded vt
    u16* xn_hi = (u16*)carve(rows * NDIM * 2);
    u16* xn_lo = (u16*)carve(rows * NDIM * 2);
    u16* wqT_hi = (u16*)carve((size_t)NQKV * NDIM * 2);
    u16* wqT_lo = (u16*)carve((size_t)NQKV * NDIM * 2);
    u16* woT_hi = (u16*)carve((size_t)NDIM * NINNER * 2);
    u16* woT_lo = (u16*)carve((size_t)NDIM * NINNER * 2);
    u16* q_hi  = (u16*)carve(hn * 2);
    u16* q_lo  = (u16*)carve(hn * 2);
    u16* k_hi  = (u16*)carve(hn * 2);
    u16* k_lo  = (u16*)carve(hn * 2);
    u16* vbuf  = (u16*)carve(hn * 2);
    u16* vt    = (u16*)carve(hnp * 2);
    u16* o_hi  = (u16*)carve(rows * NINNER * 2);
    u16* o_lo  = (u16*)carve(rows * NINNER * 2);

    ln_kernel<<<dim3((unsigned)rows), 256, 0, stream>>>(x, gamma, (u32*)xn_hi, (u32*)xn_lo);
    wtrans_kernel<<<dim3(128), 256, 0, stream>>>(wqkv, wqT_hi, wqT_lo, wout, woT_hi, woT_lo);
    qkv_kernel<<<dim3(64, 12), 256, 0, stream>>>(xn_hi, xn_lo, wqT_hi, wqT_lo,
                                                 q_hi, q_lo, k_hi, k_lo, vbuf);
    vtrans_kernel<<<dim3(NSEQ / 64, NB * NHEAD), 256, 0, stream>>>(vbuf, vt);
    attn_kernel<<<dim3(NSEQ / 32, NB * NHEAD), 512, 0, stream>>>(q_hi, q_lo, k_hi, k_lo,
                                                                 vt, bias, o_hi, o_lo);
    out_kernel<<<dim3(64, 8), 256, 0, stream>>>(o_hi, o_lo, woT_hi, woT_lo, bout, out);
}

// Round 9
// 274.356 us; speedup vs baseline: 1.0435x; 1.0435x over previous
//
#include <hip/hip_runtime.h>
#include <hip/hip_bf16.h>
#include <cstdint>

#define NB 2
#define NSEQ 2048
#define NDIM 512
#define NHEAD 8
#define DHEAD 32
#define NINNER 256
#define NQKV 768
#define LNEPS 1e-5f
#define QSCALE 0.17677669529663687f

typedef short short8 __attribute__((ext_vector_type(8)));
typedef float f32x4 __attribute__((ext_vector_type(4)));
typedef unsigned int u32x4 __attribute__((ext_vector_type(4)));
typedef unsigned int u32x2 __attribute__((ext_vector_type(2)));
typedef unsigned short u16;
typedef unsigned int u32;

__device__ __forceinline__ f32x4 mfma16(short8 a, short8 b, f32x4 c) {
    return __builtin_amdgcn_mfma_f32_16x16x32_bf16(a, b, c, 0, 0, 0);
}

__device__ __forceinline__ u16 f2bf(float a) {
    union { float f; u32 u; } x; x.f = a;
    u32 r = x.u + 0x7fffu + ((x.u >> 16) & 1u);
    return (u16)(r >> 16);
}
__device__ __forceinline__ float bf2f(u16 h) {
    union { float f; u32 u; } x; x.u = ((u32)h) << 16; return x.f;
}
__device__ __forceinline__ void split2(float a, u16& hi, u16& lo) {
    hi = f2bf(a);
    lo = f2bf(a - bf2f(hi));
}
__device__ __forceinline__ u32 pk2(float a, float b) {
    return (u32)f2bf(a) | ((u32)f2bf(b) << 16);
}

// ---------------- Kernel 1: LayerNorm + bf16 hi/lo split ----------------
__global__ __launch_bounds__(256) void ln_kernel(
    const float* __restrict__ x, const float* __restrict__ gamma,
    u32* __restrict__ xn_hi, u32* __restrict__ xn_lo)
{
    const int row = blockIdx.x;
    const int t = threadIdx.x;
    const float2 v = ((const float2*)(x + (size_t)row * NDIM))[t];
    float s1 = v.x + v.y;
    float s2 = v.x * v.x + v.y * v.y;
    #pragma unroll
    for (int off = 32; off >= 1; off >>= 1) {
        s1 += __shfl_down(s1, off);
        s2 += __shfl_down(s2, off);
    }
    __shared__ float a1[4], a2[4];
    if ((t & 63) == 0) { a1[t >> 6] = s1; a2[t >> 6] = s2; }
    __syncthreads();
    const float ts1 = a1[0] + a1[1] + a1[2] + a1[3];
    const float ts2 = a2[0] + a2[1] + a2[2] + a2[3];
    const float mu = ts1 * (1.0f / NDIM);
    const float var = ts2 * (1.0f / NDIM) - mu * mu;
    const float rs = rsqrtf(var + LNEPS);
    const float2 g = ((const float2*)gamma)[t];
    u16 h0, l0, h1, l1;
    split2((v.x - mu) * rs * g.x, h0, l0);
    split2((v.y - mu) * rs * g.y, h1, l1);
    xn_hi[(size_t)row * (NDIM / 2) + t] = (u32)h0 | ((u32)h1 << 16);
    xn_lo[(size_t)row * (NDIM / 2) + t] = (u32)l0 | ((u32)l1 << 16);
}

// ---------------- Weight transpose + split, both weights in one launch ----------------
__global__ __launch_bounds__(256) void wtrans_kernel(
    const float* __restrict__ wq, u16* __restrict__ wqT_hi, u16* __restrict__ wqT_lo,
    const float* __restrict__ wo, u16* __restrict__ woT_hi, u16* __restrict__ woT_lo)
{
    __shared__ __align__(16) u16 th[64][72], tl[64][72];
    const int t = threadIdx.x;
    const float* w; u16 *wT_hi, *wT_lo; int K, N, k0, n0;
    if (blockIdx.x < 96) {
        w = wq; wT_hi = wqT_hi; wT_lo = wqT_lo; K = NDIM; N = NQKV;
        k0 = (blockIdx.x & 7) * 64; n0 = (blockIdx.x >> 3) * 64;
    } else {
        const int b = blockIdx.x - 96;
        w = wo; wT_hi = woT_hi; wT_lo = woT_lo; K = NINNER; N = NDIM;
        k0 = (b & 3) * 64; n0 = (b >> 2) * 64;
    }
    {
        const int k = t >> 2, c = (t & 3) * 16;
        const float* src = w + (size_t)(k0 + k) * N + n0 + c;
        #pragma unroll
        for (int jj = 0; jj < 4; jj++) {
            const f32x4 w4 = *(const f32x4*)(src + jj * 4);
            #pragma unroll
            for (int e = 0; e < 4; e++) {
                u16 hh, ll;
                split2(w4[e], hh, ll);
                th[k][c + jj * 4 + e] = hh;
                tl[k][c + jj * 4 + e] = ll;
            }
        }
    }
    __syncthreads();
    {
        const int n = t >> 2, kc = (t & 3) * 16;
        u16 hb[16], lb[16];
        #pragma unroll
        for (int j = 0; j < 16; j++) { hb[j] = th[kc + j][n]; lb[j] = tl[kc + j][n]; }
        u16* dh = wT_hi + (size_t)(n0 + n) * K + k0 + kc;
        u16* dl = wT_lo + (size_t)(n0 + n) * K + k0 + kc;
        *(short8*)dh = *(short8*)hb;
        *(short8*)(dh + 8) = *(short8*)(hb + 8);
        *(short8*)dl = *(short8*)lb;
        *(short8*)(dl + 8) = *(short8*)(lb + 8);
    }
}

// ---------------- V transpose: v[bh][N][32] bf16 -> vt[bh][32][N] ----------------
__global__ __launch_bounds__(256) void vtrans_kernel(
    const u16* __restrict__ v, u16* __restrict__ vt)
{
    __shared__ __align__(16) u16 sh[64][40];
    const int t = threadIdx.x;
    const int n0 = blockIdx.x * 64;
    const int bh = blockIdx.y;
    {
        const int n = t >> 2, c = (t & 3) * 8;
        *(short8*)&sh[n][c] = *(const short8*)(v + ((size_t)bh * NSEQ + n0 + n) * DHEAD + c);
    }
    __syncthreads();
    {
        const int d = t >> 3, nc = (t & 7) * 8;
        u16 buf[8];
        #pragma unroll
        for (int j = 0; j < 8; j++) buf[j] = sh[nc + j][d];
        *(short8*)(vt + ((size_t)bh * DHEAD + d) * NSEQ + n0 + nc) = *(short8*)buf;
    }
}

// ---------------- Kernel 2: QKV GEMM (64x64 tile, 4 waves, 12 MFMA/wave-iter) ----------------
__global__ __launch_bounds__(256, 4) void qkv_kernel(
    const u16* __restrict__ xn_hi, const u16* __restrict__ xn_lo,
    const u16* __restrict__ wT_hi, const u16* __restrict__ wT_lo,
    u16* __restrict__ q_hi, u16* __restrict__ q_lo,
    u16* __restrict__ k_hi, u16* __restrict__ k_lo,
    u16* __restrict__ v)
{
    __shared__ __align__(16) u16 Ah[64][40], Al[64][40], Bh[64][40], Bl[64][40];
    const int t = threadIdx.x;
    const int wave = t >> 6, lane = t & 63;
    const int lrow = lane & 15, lquad = lane >> 4;
    const int rowBase = blockIdx.x * 64;
    const int colBase = blockIdx.y * 64;
    const int wm = (wave & 1) * 32;
    const int wn = (wave >> 1) * 32;
    const int kf = lquad * 8;
    const f32x4 zero = {0.f, 0.f, 0.f, 0.f};
    f32x4 acc[2][2];
    acc[0][0] = zero; acc[0][1] = zero; acc[1][0] = zero; acc[1][1] = zero;

    const int sr = t >> 2, sc = (t & 3) * 8;

    for (int k0 = 0; k0 < NDIM; k0 += 32) {
        __syncthreads();
        *(short8*)&Ah[sr][sc] = *(const short8*)(xn_hi + (size_t)(rowBase + sr) * NDIM + k0 + sc);
        *(short8*)&Al[sr][sc] = *(const short8*)(xn_lo + (size_t)(rowBase + sr) * NDIM + k0 + sc);
        *(short8*)&Bh[sr][sc] = *(const short8*)(wT_hi + (size_t)(colBase + sr) * NDIM + k0 + sc);
        *(short8*)&Bl[sr][sc] = *(const short8*)(wT_lo + (size_t)(colBase + sr) * NDIM + k0 + sc);
        __syncthreads();
        const short8 a0h = *(const short8*)&Ah[wm + lrow][kf];
        const short8 a0l = *(const short8*)&Al[wm + lrow][kf];
        const short8 a1h = *(const short8*)&Ah[wm + 16 + lrow][kf];
        const short8 a1l = *(const short8*)&Al[wm + 16 + lrow][kf];
        const short8 b0h = *(const short8*)&Bh[wn + lrow][kf];
        const short8 b0l = *(const short8*)&Bl[wn + lrow][kf];
        const short8 b1h = *(const short8*)&Bh[wn + 16 + lrow][kf];
        const short8 b1l = *(const short8*)&Bl[wn + 16 + lrow][kf];
        acc[0][0] = mfma16(a0h, b0h, acc[0][0]); acc[0][0] = mfma16(a0h, b0l, acc[0][0]); acc[0][0] = mfma16(a0l, b0h, acc[0][0]);
        acc[0][1] = mfma16(a0h, b1h, acc[0][1]); acc[0][1] = mfma16(a0h, b1l, acc[0][1]); acc[0][1] = mfma16(a0l, b1h, acc[0][1]);
        acc[1][0] = mfma16(a1h, b0h, acc[1][0]); acc[1][0] = mfma16(a1h, b0l, acc[1][0]); acc[1][0] = mfma16(a1l, b0h, acc[1][0]);
        acc[1][1] = mfma16(a1h, b1h, acc[1][1]); acc[1][1] = mfma16(a1h, b1l, acc[1][1]); acc[1][1] = mfma16(a1l, b1h, acc[1][1]);
    }

    #pragma unroll
    for (int mi = 0; mi < 2; mi++) {
        #pragma unroll
        for (int ni = 0; ni < 2; ni++) {
            #pragma unroll
            for (int r = 0; r < 4; r++) {
                const int grow = rowBase + wm + mi * 16 + lquad * 4 + r;
                const int gcol = colBase + wn + ni * 16 + lrow;
                const float val = acc[mi][ni][r];
                const int bidx = grow >> 11;
                const int n = grow & (NSEQ - 1);
                const int sec = gcol >> 8;          // 0=q 1=k 2=v
                const int idx = gcol & 255;
                const int head = idx >> 5, d = idx & 31;
                const int bh = bidx * NHEAD + head;
                if (sec == 0) {
                    u16 hh, ll;
                    split2(val * QSCALE, hh, ll);
                    const size_t a = ((size_t)bh * NSEQ + n) * DHEAD + d;
                    q_hi[a] = hh; q_lo[a] = ll;
                } else if (sec == 1) {
                    u16 hh, ll;
                    split2(val, hh, ll);
                    const size_t a = ((size_t)bh * NSEQ + n) * DHEAD + d;
                    k_hi[a] = hh; k_lo[a] = ll;
                } else {
                    v[((size_t)bh * NSEQ + n) * DHEAD + d] = f2bf(val);
                }
            }
        }
    }
}

// ---------------- Kernel 3: flash attention, batch-shared bias ----------------
// Block = 512 threads = 8 waves, one HEAD, 32-query tile, BOTH batches.
// Grid 64x8 = 512 blocks. Wave w: batch = w&1, key slice = w>>1 covers
// keys [(w>>1)*512, +512), 16 iterations of 32 keys. Each wave computes
// both 16-q fragments of the 32-q tile FOR ITS BATCH.
// KEY CHANGE vs R2: bias is (head, N, N) broadcast over batch, so the
// batch-0 and batch-1 waves of a pair issue IDENTICAL bias addresses at
// the same loop phase -> logical bias traffic halves (read-once total
// across the grid); requests dedup in L1/L2. Inner loop otherwise
// byte-identical to the verified R0/R2 structure.
__global__ __launch_bounds__(512, 4) void attn_kernel(
    const u16* __restrict__ q_hi, const u16* __restrict__ q_lo,
    const u16* __restrict__ k_hi, const u16* __restrict__ k_lo,
    const u16* __restrict__ vt,
    const float* __restrict__ bias,
    u16* __restrict__ o_hi, u16* __restrict__ o_lo)
{
    __shared__ __align__(16) float cA[2][2][4][64][4];   // [batch][frag][kslice][lane][4]
    __shared__ __align__(16) float cB[2][2][4][64][4];
    __shared__ float cl[2][2][4][16];
    const int t = threadIdx.x;
    const int wave = t >> 6, lane = t & 63;
    const int lrow = lane & 15, lquad = lane >> 4;
    const int batch = wave & 1, kslice = wave >> 1;
    const int head = blockIdx.y;
    const int qb = blockIdx.x * 32;
    const size_t qkb = (size_t)(batch * NHEAD + head) * NSEQ * DHEAD;
    // two 16-q fragments (rows qb..qb+16 and qb+16..qb+32) for this batch
    const size_t qoff0 = (size_t)(qb + lrow) * DHEAD + lquad * 8;
    const size_t qoff1 = (size_t)(qb + 16 + lrow) * DHEAD + lquad * 8;
    const short8 qh0 = *(const short8*)(q_hi + qkb + qoff0);
    const short8 ql0 = *(const short8*)(q_lo + qkb + qoff0);
    const short8 qh1 = *(const short8*)(q_hi + qkb + qoff1);
    const short8 ql1 = *(const short8*)(q_lo + qkb + qoff1);
    const f32x4 zero = {0.f, 0.f, 0.f, 0.f};
    f32x4 accA0 = zero, accB0 = zero, accA1 = zero, accB1 = zero;
    float lp0 = 0.f, lp1 = 0.f;
    const int kperm = ((lrow >> 2) << 3) | (lrow & 3);
    // bias: NO batch term — shared by the batch-pair waves
    const float* bptr0 = bias + (size_t)head * NSEQ * NSEQ + (size_t)(qb + lrow) * NSEQ;
    const float* bptr1 = bptr0 + 16 * NSEQ;
    const int kt0 = kslice * 512;

    // prefetch bias for iter 0
    f32x4 b00 = *(const f32x4*)(bptr0 + kt0 + lquad * 8);
    f32x4 b01 = *(const f32x4*)(bptr0 + kt0 + lquad * 8 + 4);
    f32x4 b10 = *(const f32x4*)(bptr1 + kt0 + lquad * 8);
    f32x4 b11 = *(const f32x4*)(bptr1 + kt0 + lquad * 8 + 4);

    for (int i = 0; i < 16; i++) {
        const int kt = kt0 + i * 32;
        // K / V loads for this tile (this batch; L2-resident streams)
        const size_t kof = (size_t)(kt + kperm) * DHEAD + lquad * 8;
        const short8 k0h = *(const short8*)(k_hi + qkb + kof);
        const short8 k0l = *(const short8*)(k_lo + qkb + kof);
        const short8 k1h = *(const short8*)(k_hi + qkb + kof + 4 * DHEAD);
        const short8 k1l = *(const short8*)(k_lo + qkb + kof + 4 * DHEAD);
        const short8 va0 = *(const short8*)(vt + qkb + (size_t)lrow * NSEQ + kt + lquad * 8);
        const short8 va1 = *(const short8*)(vt + qkb + (size_t)(16 + lrow) * NSEQ + kt + lquad * 8);
        // prefetch bias for next tile
        const int ktn = kt0 + ((i + 1) & 15) * 32;
        const f32x4 nb00 = *(const f32x4*)(bptr0 + ktn + lquad * 8);
        const f32x4 nb01 = *(const f32x4*)(bptr0 + ktn + lquad * 8 + 4);
        const f32x4 nb10 = *(const f32x4*)(bptr1 + ktn + lquad * 8);
        const f32x4 nb11 = *(const f32x4*)(bptr1 + ktn + lquad * 8 + 4);

        // ---- q-frag 0 ----
        {
            f32x4 c0 = zero, c1 = zero;
            c0 = mfma16(k0h, qh0, c0); c0 = mfma16(k0h, ql0, c0); c0 = mfma16(k0l, qh0, c0);
            c1 = mfma16(k1h, qh0, c1); c1 = mfma16(k1h, ql0, c1); c1 = mfma16(k1l, qh0, c1);
            f32x4 p0, p1;
            #pragma unroll
            for (int r = 0; r < 4; r++) {
                p0[r] = __expf(c0[r] + b00[r]);
                p1[r] = __expf(c1[r] + b01[r]);
            }
            lp0 += (p0[0] + p0[1]) + (p0[2] + p0[3]) + (p1[0] + p1[1]) + (p1[2] + p1[3]);
            union { u32x4 u; short8 s; } cv;
            cv.u[0] = pk2(p0[0], p0[1]);
            cv.u[1] = pk2(p0[2], p0[3]);
            cv.u[2] = pk2(p1[0], p1[1]);
            cv.u[3] = pk2(p1[2], p1[3]);
            accA0 = mfma16(va0, cv.s, accA0);
            accB0 = mfma16(va1, cv.s, accB0);
        }
        // ---- q-frag 1 ----
        {
            f32x4 c0 = zero, c1 = zero;
            c0 = mfma16(k0h, qh1, c0); c0 = mfma16(k0h, ql1, c0); c0 = mfma16(k0l, qh1, c0);
            c1 = mfma16(k1h, qh1, c1); c1 = mfma16(k1h, ql1, c1); c1 = mfma16(k1l, qh1, c1);
            f32x4 p0, p1;
            #pragma unroll
            for (int r = 0; r < 4; r++) {
                p0[r] = __expf(c0[r] + b10[r]);
                p1[r] = __expf(c1[r] + b11[r]);
            }
            lp1 += (p0[0] + p0[1]) + (p0[2] + p0[3]) + (p1[0] + p1[1]) + (p1[2] + p1[3]);
            union { u32x4 u; short8 s; } cv;
            cv.u[0] = pk2(p0[0], p0[1]);
            cv.u[1] = pk2(p0[2], p0[3]);
            cv.u[2] = pk2(p1[0], p1[1]);
            cv.u[3] = pk2(p1[2], p1[3]);
            accA1 = mfma16(va0, cv.s, accA1);
            accB1 = mfma16(va1, cv.s, accB1);
        }
        b00 = nb00; b01 = nb01; b10 = nb10; b11 = nb11;
    }

    // per-lane lp covers keys quad*8..+7 of this slice; reduce across quads
    lp0 += __shfl_xor(lp0, 16); lp0 += __shfl_xor(lp0, 32);
    lp1 += __shfl_xor(lp1, 16); lp1 += __shfl_xor(lp1, 32);

    *(f32x4*)&cA[batch][0][kslice][lane][0] = accA0;
    *(f32x4*)&cB[batch][0][kslice][lane][0] = accB0;
    *(f32x4*)&cA[batch][1][kslice][lane][0] = accA1;
    *(f32x4*)&cB[batch][1][kslice][lane][0] = accB1;
    if (lquad == 0) {
        cl[batch][0][kslice][lrow] = lp0;
        cl[batch][1][kslice][lrow] = lp1;
    }
    __syncthreads();
    {
        // 8 waves = 2 batches x 2 frags x 2 column-halves
        const int bb = wave & 1, s = (wave >> 1) & 1, part = wave >> 2;
        const float (*src)[64][4] = part ? (const float (*)[64][4])cB[bb][s]
                                         : (const float (*)[64][4])cA[bb][s];
        f32x4 sv = *(const f32x4*)&src[0][lane][0];
        #pragma unroll
        for (int w = 1; w < 4; w++) {
            sv += *(const f32x4*)&src[w][lane][0];
        }
        const float lt = cl[bb][s][0][lrow] + cl[bb][s][1][lrow]
                       + cl[bb][s][2][lrow] + cl[bb][s][3][lrow];
        const float inv = 1.0f / lt;
        const int q = qb + s * 16 + lrow;
        const size_t base = ((size_t)bb * NSEQ + q) * NINNER + head * DHEAD + part * 16 + lquad * 4;
        u16 h[4], l[4];
        #pragma unroll
        for (int r = 0; r < 4; r++) {
            split2(sv[r] * inv, h[r], l[r]);
        }
        *(u32x2*)&o_hi[base] = *(u32x2*)&h[0];
        *(u32x2*)&o_lo[base] = *(u32x2*)&l[0];
    }
}

// ---------------- Kernel 4: output projection (64x64 tile) + bias ----------------
__global__ __launch_bounds__(256, 4) void out_kernel(
    const u16* __restrict__ o_hi, const u16* __restrict__ o_lo,
    const u16* __restrict__ wT_hi, const u16* __restrict__ wT_lo,
    const float* __restrict__ b_out,
    float* __restrict__ out)
{
    __shared__ __align__(16) u16 Ah[64][40], Al[64][40], Bh[64][40], Bl[64][40];
    const int t = threadIdx.x;
    const int wave = t >> 6, lane = t & 63;
    const int lrow = lane & 15, lquad = lane >> 4;
    const int rowBase = blockIdx.x * 64;
    const int colBase = blockIdx.y * 64;
    const int wm = (wave & 1) * 32;
    const int wn = (wave >> 1) * 32;
    const int kf = lquad * 8;
    const f32x4 zero = {0.f, 0.f, 0.f, 0.f};
    f32x4 acc[2][2];
    acc[0][0] = zero; acc[0][1] = zero; acc[1][0] = zero; acc[1][1] = zero;

    const int sr = t >> 2, sc = (t & 3) * 8;

    for (int k0 = 0; k0 < NINNER; k0 += 32) {
        __syncthreads();
        *(short8*)&Ah[sr][sc] = *(const short8*)(o_hi + (size_t)(rowBase + sr) * NINNER + k0 + sc);
        *(short8*)&Al[sr][sc] = *(const short8*)(o_lo + (size_t)(rowBase + sr) * NINNER + k0 + sc);
        *(short8*)&Bh[sr][sc] = *(const short8*)(wT_hi + (size_t)(colBase + sr) * NINNER + k0 + sc);
        *(short8*)&Bl[sr][sc] = *(const short8*)(wT_lo + (size_t)(colBase + sr) * NINNER + k0 + sc);
        __syncthreads();
        const short8 a0h = *(const short8*)&Ah[wm + lrow][kf];
        const short8 a0l = *(const short8*)&Al[wm + lrow][kf];
        const short8 a1h = *(const short8*)&Ah[wm + 16 + lrow][kf];
        const short8 a1l = *(const short8*)&Al[wm + 16 + lrow][kf];
        const short8 b0h = *(const short8*)&Bh[wn + lrow][kf];
        const short8 b0l = *(const short8*)&Bl[wn + lrow][kf];
        const short8 b1h = *(const short8*)&Bh[wn + 16 + lrow][kf];
        const short8 b1l = *(const short8*)&Bl[wn + 16 + lrow][kf];
        acc[0][0] = mfma16(a0h, b0h, acc[0][0]); acc[0][0] = mfma16(a0h, b0l, acc[0][0]); acc[0][0] = mfma16(a0l, b0h, acc[0][0]);
        acc[0][1] = mfma16(a0h, b1h, acc[0][1]); acc[0][1] = mfma16(a0h, b1l, acc[0][1]); acc[0][1] = mfma16(a0l, b1h, acc[0][1]);
        acc[1][0] = mfma16(a1h, b0h, acc[1][0]); acc[1][0] = mfma16(a1h, b0l, acc[1][0]); acc[1][0] = mfma16(a1l, b0h, acc[1][0]);
        acc[1][1] = mfma16(a1h, b1h, acc[1][1]); acc[1][1] = mfma16(a1h, b1l, acc[1][1]); acc[1][1] = mfma16(a1l, b1h, acc[1][1]);
    }

    #pragma unroll
    for (int mi = 0; mi < 2; mi++) {
        #pragma unroll
        for (int ni = 0; ni < 2; ni++) {
            #pragma unroll
            for (int r = 0; r < 4; r++) {
                const int grow = rowBase + wm + mi * 16 + lquad * 4 + r;
                const int gcol = colBase + wn + ni * 16 + lrow;
                out[(size_t)grow * NDIM + gcol] = acc[mi][ni][r] + b_out[gcol];
            }
        }
    }
}

extern "C" void kernel_launch(void* const* d_in, const int* in_sizes, int n_in,
                              void* d_out, int out_size, void* d_ws, size_t ws_size,
                              hipStream_t stream)
{
    (void)in_sizes; (void)n_in; (void)out_size; (void)ws_size;
    const float* x     = (const float*)d_in[0];
    const float* bias  = (const float*)d_in[1];
    const float* gamma = (const float*)d_in[2];
    const float* wqkv  = (const float*)d_in[3];
    const float* wout  = (const float*)d_in[4];
    const float* bout  = (const float*)d_in[5];
    float* out = (float*)d_out;

    char* ws = (char*)d_ws;
    size_t off = 0;
    auto carve = [&](size_t bytes) -> void* {
        void* p = (void*)(ws + off);
        off += (bytes + 255) & ~(size_t)255;
        return p;
    };
    const size_t rows = (size_t)NB * NSEQ;                 // 4096
    const size_t hn = (size_t)NB * NHEAD * NSEQ * DHEAD;   // 1,048,576
    u16* xn_hi = (u16*)carve(rows * NDIM * 2);
    u16* xn_lo = (u16*)carve(rows * NDIM * 2);
    u16* wqT_hi = (u16*)carve((size_t)NQKV * NDIM * 2);
    u16* wqT_lo = (u16*)carve((size_t)NQKV * NDIM * 2);
    u16* woT_hi = (u16*)carve((size_t)NDIM * NINNER * 2);
    u16* woT_lo = (u16*)carve((size_t)NDIM * NINNER * 2);
    u16* q_hi  = (u16*)carve(hn * 2);
    u16* q_lo  = (u16*)carve(hn * 2);
    u16* k_hi  = (u16*)carve(hn * 2);
    u16* k_lo  = (u16*)carve(hn * 2);
    u16* vbuf  = (u16*)carve(hn * 2);
    u16* vt    = (u16*)carve(hn * 2);
    u16* o_hi  = (u16*)carve(rows * NINNER * 2);
    u16* o_lo  = (u16*)carve(rows * NINNER * 2);

    ln_kernel<<<dim3((unsigned)rows), 256, 0, stream>>>(x, gamma, (u32*)xn_hi, (u32*)xn_lo);
    wtrans_kernel<<<dim3(128), 256, 0, stream>>>(wqkv, wqT_hi, wqT_lo, wout, woT_hi, woT_lo);
    qkv_kernel<<<dim3(64, 12), 256, 0, stream>>>(xn_hi, xn_lo, wqT_hi, wqT_lo,
                                                 q_hi, q_lo, k_hi, k_lo, vbuf);
    vtrans_kernel<<<dim3(NSEQ / 64, NB * NHEAD), 256, 0, stream>>>(vbuf, vt);
    attn_kernel<<<dim3(NSEQ / 32, NHEAD), 512, 0, stream>>>(q_hi, q_lo, k_hi, k_lo,
                                                            vt, bias, o_hi, o_lo);
    out_kernel<<<dim3(64, 8), 256, 0, stream>>>(o_hi, o_lo, woT_hi, woT_lo, bout, out);
}